// Round 6
// baseline (106.752 us; speedup 1.0000x reference)
//
#include <hip/hip_runtime.h>
#include <math.h>

// CapLayer, single-node, protocol-free. Routing degeneracy (b=0 init ->
// softmax uniform -> o-independent v -> b stays o-constant all 3 iters):
//   out[b,o,:] = squash( colsum(pred[b]) / 64 )   broadcast over o
//   colsum[b,d] = sum_s sum_i W[s,d,i] * U[b,s,i]
//   U[b,s,i]    = sum_{p<256} x[b, s*8192 + p*32 + i]
//
// R6: one block per b (64 blocks x 1024 threads). No ws, no memset, no
// atomics, no cross-block protocol, one graph node. Wave w reduces chunks
// s=2w,2w+1 (all loads coalesced 1KB/instr), then contracts W s-slices
// 2w,2w+1 with coalesced W loads + xor-tree over i4 fragments (fixes R5's
// stride-128B W pattern), LDS tree over s, squash in wave 0, 16KB write.

__global__ __launch_bounds__(1024) void k_caplayer(const float* __restrict__ x,
                                                   const float* __restrict__ W,
                                                   float* __restrict__ out) {
    const int b  = blockIdx.x;
    const int t  = threadIdx.x;
    const int w  = t >> 6;      // wave 0..15 -> s pair {2w, 2w+1}
    const int ln = t & 63;

    __shared__ float U[32][32];     // U[s][i]
    __shared__ float pb[2048];      // pb[s*64 + d]
    __shared__ float vsh[64];

    // ---- Phase A: reduce x-chunks over p. Lane ln, instr j reads float4
    // (ln + 64j) of its chunk: i4 = ln&7 fixed, p = ln>>3 + 8j. ----
    const float4* base = reinterpret_cast<const float4*>(x) + (size_t)b * 65536;
    const float4* c0 = base + (size_t)(2 * w) * 2048 + ln;
    const float4* c1 = c0 + 2048;
    float4 a0 = make_float4(0.f, 0.f, 0.f, 0.f);
    float4 a1 = make_float4(0.f, 0.f, 0.f, 0.f);
#pragma unroll
    for (int kb = 0; kb < 4; ++kb) {
        float4 t0[8], t1[8];
#pragma unroll
        for (int j = 0; j < 8; ++j) t0[j] = c0[(size_t)64 * (8 * kb + j)];
#pragma unroll
        for (int j = 0; j < 8; ++j) t1[j] = c1[(size_t)64 * (8 * kb + j)];
#define SUM8C(T, c) ((((T[0].c + T[1].c) + (T[2].c + T[3].c)) + \
                      ((T[4].c + T[5].c) + (T[6].c + T[7].c))))
        a0.x += SUM8C(t0, x); a0.y += SUM8C(t0, y);
        a0.z += SUM8C(t0, z); a0.w += SUM8C(t0, w);
        a1.x += SUM8C(t1, x); a1.y += SUM8C(t1, y);
        a1.z += SUM8C(t1, z); a1.w += SUM8C(t1, w);
#undef SUM8C
    }
#pragma unroll
    for (int off = 8; off <= 32; off <<= 1) {   // combine lanes sharing i4
        a0.x += __shfl_xor(a0.x, off, 64);
        a0.y += __shfl_xor(a0.y, off, 64);
        a0.z += __shfl_xor(a0.z, off, 64);
        a0.w += __shfl_xor(a0.w, off, 64);
        a1.x += __shfl_xor(a1.x, off, 64);
        a1.y += __shfl_xor(a1.y, off, 64);
        a1.z += __shfl_xor(a1.z, off, 64);
        a1.w += __shfl_xor(a1.w, off, 64);
    }
    if (ln < 8) {
        *reinterpret_cast<float4*>(&U[2 * w][4 * ln])     = a0;
        *reinterpret_cast<float4*>(&U[2 * w + 1][4 * ln]) = a1;
    }
    __syncthreads();

    // ---- Phase B: wave w contracts W slices s=2w,2w+1 (coalesced).
    // Lane ln, instr j reads W float4 (s*512 + ln + 64j): d = ln>>3 + 8j,
    // i4 = ln&7. Dot with U fragment, xor-tree over i4 (off 1,2,4). ----
    const int i4 = ln & 7;
    const float4 u0 = *reinterpret_cast<const float4*>(&U[2 * w][4 * i4]);
    const float4 u1 = *reinterpret_cast<const float4*>(&U[2 * w + 1][4 * i4]);
    const float4* Ws = reinterpret_cast<const float4*>(W) + (size_t)(2 * w) * 512 + ln;
    float p[16];
#pragma unroll
    for (int j = 0; j < 8; ++j) {
        const float4 w4 = Ws[64 * j];
        p[j] = w4.x * u0.x + w4.y * u0.y + w4.z * u0.z + w4.w * u0.w;
    }
#pragma unroll
    for (int j = 0; j < 8; ++j) {
        const float4 w4 = Ws[512 + 64 * j];
        p[8 + j] = w4.x * u1.x + w4.y * u1.y + w4.z * u1.z + w4.w * u1.w;
    }
#pragma unroll
    for (int j = 0; j < 16; ++j) {
        p[j] += __shfl_xor(p[j], 1, 64);
        p[j] += __shfl_xor(p[j], 2, 64);
        p[j] += __shfl_xor(p[j], 4, 64);
    }
    if (i4 == 0) {
        const int dbase = ln >> 3;   // 0..7
#pragma unroll
        for (int j = 0; j < 8; ++j) pb[(2 * w) * 64 + dbase + 8 * j] = p[j];
#pragma unroll
        for (int j = 0; j < 8; ++j) pb[(2 * w + 1) * 64 + dbase + 8 * j] = p[8 + j];
    }
    __syncthreads();

    // ---- s-tree: pb[s*64+d] summed over s (stride-preserving pairs) ----
    pb[t] += pb[t + 1024];
    __syncthreads();
    if (t < 512) pb[t] += pb[t + 512];
    __syncthreads();
    if (t < 256) pb[t] += pb[t + 256];
    __syncthreads();
    if (t < 128) pb[t] += pb[t + 128];
    __syncthreads();
    if (t < 64) {
        const float tot = pb[t] + pb[t + 64];
        const float s1  = tot * (1.0f / 64.0f);
        float sq = s1 * s1;
#pragma unroll
        for (int off = 32; off >= 1; off >>= 1) sq += __shfl_xor(sq, off, 64);
        const float coeff = sqrtf(sq) / (1.0f + sq);   // n^2/(1+n^2)/n
        vsh[t] = s1 * coeff;
    }
    __syncthreads();

    // ---- broadcast write: out[b,o,d] = vsh[d], 1 float4/thread ----
    float4* ob4 = reinterpret_cast<float4*>(out + (size_t)b * 4096);
    ob4[t] = *reinterpret_cast<const float4*>(&vsh[(4 * t) & 63]);
}

extern "C" void kernel_launch(void* const* d_in, const int* in_sizes, int n_in,
                              void* d_out, int out_size, void* d_ws, size_t ws_size,
                              hipStream_t stream) {
    const float* x = (const float*)d_in[0];   // [64, 1024, 16, 16] fp32
    const float* W = (const float*)d_in[1];   // [32, 64, 32] fp32
    float* out = (float*)d_out;               // [64, 64, 64] fp32
    (void)d_ws; (void)ws_size;                // no workspace, no memset

    k_caplayer<<<64, 1024, 0, stream>>>(x, W, out);
}